// Round 3
// baseline (98.156 us; speedup 1.0000x reference)
//
#include <hip/hip_runtime.h>
#include <hip/hip_cooperative_groups.h>

namespace cg = cooperative_groups;

// GeometryRefiner: 3 Adam iterations on analytic gradient of
// bond + angle + clash + restraint loss. B=2, S=256, A=5.
// Single cooperative kernel: phase1 grad(x0)->g1 | grid.sync |
// phase2 adam1(redundant)+grad(x1)->g2 | grid.sync |
// phase3 adam1+2(redundant)+grad(x2)+adam3 -> out.

#define S_ 256
#define A_ 5
#define NATOM 1280           // S_*A_
#define NB3 3840             // NATOM*3
#define NF4 960              // NB3/4
#define NEL 7680             // B*NB3
#define SPLIT 16
#define ATOMS_PER_BLOCK 16   // 256/SPLIT
#define BLOCKS_PER_BATCH 80  // NATOM/ATOMS_PER_BLOCK
#define GRID_ (2 * BLOCKS_PER_BATCH)

// 2*W/(normalizer) coefficients (d/dx of squared terms)
#define COEF_BOND2  (10.0f/1275.0f)
#define COEF_ANGLE2 (10.0f/1536.0f)
#define COEF_CLASH2 (20.0f/1619250.0f)
#define COEF_REST2  (2.0f/32640.0f)
#define TGT_ANG 1.91113553f               // 109.5 * pi / 180

__device__ __forceinline__ float adam_step1(float x, float g) {
    float mn = 0.1f * g;
    float vn = 0.001f * g * g;
    float mh = mn / 0.1f;
    float vh = vn / 0.001f;
    return x - 0.01f * mh / (sqrtf(vh) + 1e-8f);
}

__device__ __forceinline__ float adam_step2(float x, float g1, float g2) {
    float m1 = 0.1f * g1;
    float v1 = 0.001f * g1 * g1;
    float mh1 = m1 / 0.1f;
    float vh1 = v1 / 0.001f;
    float x1 = x - 0.01f * mh1 / (sqrtf(vh1) + 1e-8f);
    float m2 = 0.9f * m1 + 0.1f * g2;
    float v2 = 0.999f * v1 + 0.001f * g2 * g2;
    float mh2 = m2 / 0.19f;
    float vh2 = v2 / 0.001999f;
    return x1 - 0.01f * mh2 / (sqrtf(vh2) + 1e-8f);
}

__device__ __forceinline__ void angle_accum(const float* xs, int q, int role,
                                            float& gx, float& gy, float& gz) {
    const float* P = xs + (q - 1) * 3;
    const float* Q = xs + q * 3;
    const float* R = xs + (q + 1) * 3;
    float v1x = P[0] - Q[0], v1y = P[1] - Q[1], v1z = P[2] - Q[2];
    float v2x = R[0] - Q[0], v2y = R[1] - Q[1], v2z = R[2] - Q[2];
    float n1 = sqrtf(v1x * v1x + v1y * v1y + v1z * v1z);
    float n2 = sqrtf(v2x * v2x + v2y * v2y + v2z * v2z);
    float n1m = fmaxf(n1, 1e-8f), n2m = fmaxf(n2, 1e-8f);
    float dot = v1x * v2x + v1y * v2y + v1z * v2z;
    float inv1 = 1.0f / n1m, inv2 = 1.0f / n2m;
    float inv12 = inv1 * inv2;
    float cosv = dot * inv12;
    float cc = fminf(fmaxf(cosv, -1.0f), 1.0f);
    float ang = acosf(cc);
    float G = 0.0f;
    if (cosv > -1.0f && cosv < 1.0f) {
        G = -COEF_ANGLE2 * (ang - TGT_ANG) * rsqrtf(1.0f - cosv * cosv);
    }
    float a1 = cosv * inv1 * inv1, a2 = cosv * inv2 * inv2;
    float d1x = inv12 * v2x - a1 * v1x;
    float d1y = inv12 * v2y - a1 * v1y;
    float d1z = inv12 * v2z - a1 * v1z;
    float d2x = inv12 * v1x - a2 * v2x;
    float d2y = inv12 * v1y - a2 * v2y;
    float d2z = inv12 * v1z - a2 * v2z;
    if (role == 0)      { gx += G * d1x; gy += G * d1y; gz += G * d1z; }
    else if (role == 2) { gx += G * d2x; gy += G * d2y; gz += G * d2z; }
    else                { gx -= G * (d1x + d2x); gy -= G * (d1y + d2y); gz -= G * (d1z + d2z); }
}

// Full gradient for atom n; valid in (tx,ty,tz) at sub==0 after return.
__device__ __forceinline__ void grad_body(const float* xs, const float* rb,
                                          int n, int sub,
                                          float& tx, float& ty, float& tz) {
    const int s = n / A_;
    const int a = n - s * A_;
    const float xn0 = xs[n * 3], xn1 = xs[n * 3 + 1], xn2 = xs[n * 3 + 2];

    // clash partial over residues mr = sub, sub+16, ...
    float cgx = 0.f, cgy = 0.f, cgz = 0.f;
    for (int mr = sub; mr < S_; mr += SPLIT) {
        int dres = mr - s;
        if (dres >= -1 && dres <= 1) continue;
        const float* xm = xs + mr * 15;
        #pragma unroll
        for (int ma = 0; ma < A_; ++ma) {
            float dx = xn0 - xm[ma * 3 + 0];
            float dy = xn1 - xm[ma * 3 + 1];
            float dz = xn2 - xm[ma * 3 + 2];
            float d2 = dx * dx + dy * dy + dz * dz;
            if (d2 > 1e-12f && d2 < 4.0f) {
                float inv = rsqrtf(d2);
                cgx += dx * inv; cgy += dy * inv; cgz += dz * inv;
            }
        }
    }

    // restraint partial (rep atoms only, a == 0; rep index i = s)
    float rgx = 0.f, rgy = 0.f, rgz = 0.f;
    if (a == 0) {
        const int i = s;
        for (int j = sub; j < S_; j += SPLIT) {
            if (j == i) continue;
            const float* xj = xs + j * 15;
            float dx = xn0 - xj[0], dy = xn1 - xj[1], dz = xn2 - xj[2];
            float d2 = dx * dx + dy * dy + dz * dz;
            if (d2 > 1e-12f) {
                float inv = rsqrtf(d2);
                float dr = d2 * inv;
                float rv = (i < j) ? rb[i * S_ + j] : rb[j * S_ + i];
                float w = (dr - rv) * inv;
                rgx += w * dx; rgy += w * dy; rgz += w * dz;
            }
        }
    }

    tx = -COEF_CLASH2 * cgx + COEF_REST2 * rgx;
    ty = -COEF_CLASH2 * cgy + COEF_REST2 * rgy;
    tz = -COEF_CLASH2 * cgz + COEF_REST2 * rgz;
    #pragma unroll
    for (int m = 1; m < SPLIT; m <<= 1) {
        tx += __shfl_xor(tx, m);
        ty += __shfl_xor(ty, m);
        tz += __shfl_xor(tz, m);
    }

    if (sub == 0) {
        if (n >= 1 && n <= 1275) {               // left bond (n-1, n)
            float dx = xn0 - xs[(n - 1) * 3];
            float dy = xn1 - xs[(n - 1) * 3 + 1];
            float dz = xn2 - xs[(n - 1) * 3 + 2];
            float d2 = dx * dx + dy * dy + dz * dz;
            float inv = rsqrtf(d2);
            float w = COEF_BOND2 * (1.0f - 1.5f * inv);
            tx += w * dx; ty += w * dy; tz += w * dz;
        }
        if (n <= 1274) {                         // right bond (n, n+1)
            float dx = xn0 - xs[(n + 1) * 3];
            float dy = xn1 - xs[(n + 1) * 3 + 1];
            float dz = xn2 - xs[(n + 1) * 3 + 2];
            float d2 = dx * dx + dy * dy + dz * dz;
            float inv = rsqrtf(d2);
            float w = COEF_BOND2 * (1.0f - 1.5f * inv);
            tx += w * dx; ty += w * dy; tz += w * dz;
        }
        if (a <= A_ - 3) angle_accum(xs, n + 1, 0, tx, ty, tz);
        if (a >= 1 && a <= A_ - 2) angle_accum(xs, n, 1, tx, ty, tz);
        if (a >= 2) angle_accum(xs, n - 1, 2, tx, ty, tz);
    }
}

__global__ __launch_bounds__(256) void k_fused(const float* __restrict__ x0,
                                               const float* __restrict__ restr,
                                               float* __restrict__ g1,
                                               float* __restrict__ g2,
                                               float* __restrict__ out) {
    __shared__ float xs[NB3];
    const int b = blockIdx.x / BLOCKS_PER_BATCH;
    const int base = (blockIdx.x % BLOCKS_PER_BATCH) * ATOMS_PER_BLOCK;
    const float* xb  = x0 + b * NB3;
    const float* rb  = restr + b * (S_ * S_);
    float* g1b = g1 + b * NB3;
    float* g2b = g2 + b * NB3;
    const int la  = threadIdx.x >> 4;
    const int sub = threadIdx.x & (SPLIT - 1);
    const int n = base + la;
    cg::grid_group grid = cg::this_grid();
    float tx, ty, tz;

    // ---- phase 1: g1 = grad(x0)
    for (int i = threadIdx.x; i < NF4; i += 256)
        ((float4*)xs)[i] = ((const float4*)xb)[i];
    __syncthreads();
    grad_body(xs, rb, n, sub, tx, ty, tz);
    if (sub == 0) {
        float* go = g1b + n * 3;
        go[0] = tx; go[1] = ty; go[2] = tz;
    }
    grid.sync();

    // ---- phase 2: x1 = adam1(x0, g1) staged redundantly; g2 = grad(x1)
    for (int i = threadIdx.x; i < NF4; i += 256) {
        float4 xv = ((const float4*)xb)[i];
        float4 gv = ((const float4*)g1b)[i];
        float4 o;
        o.x = adam_step1(xv.x, gv.x);
        o.y = adam_step1(xv.y, gv.y);
        o.z = adam_step1(xv.z, gv.z);
        o.w = adam_step1(xv.w, gv.w);
        ((float4*)xs)[i] = o;
    }
    __syncthreads();
    grad_body(xs, rb, n, sub, tx, ty, tz);
    if (sub == 0) {
        float* go = g2b + n * 3;
        go[0] = tx; go[1] = ty; go[2] = tz;
    }
    grid.sync();

    // ---- phase 3: x2 = adam2(x0, g1, g2) staged redundantly; g3 = grad(x2);
    //               out = adam3(x2, g1, g2, g3)
    for (int i = threadIdx.x; i < NF4; i += 256) {
        float4 xv = ((const float4*)xb)[i];
        float4 a1 = ((const float4*)g1b)[i];
        float4 a2 = ((const float4*)g2b)[i];
        float4 o;
        o.x = adam_step2(xv.x, a1.x, a2.x);
        o.y = adam_step2(xv.y, a1.y, a2.y);
        o.z = adam_step2(xv.z, a1.z, a2.z);
        o.w = adam_step2(xv.w, a1.w, a2.w);
        ((float4*)xs)[i] = o;
    }
    __syncthreads();
    grad_body(xs, rb, n, sub, tx, ty, tz);
    if (sub == 0) {
        const float* g1p = g1b + n * 3;
        const float* g2p = g2b + n * 3;
        float g3[3] = {tx, ty, tz};
        float* go = out + b * NB3 + n * 3;
        #pragma unroll
        for (int c = 0; c < 3; ++c) {
            float G1 = g1p[c], G2 = g2p[c], G3 = g3[c];
            float m1 = 0.1f * G1;
            float v1 = 0.001f * G1 * G1;
            float m2 = 0.9f * m1 + 0.1f * G2;
            float v2 = 0.999f * v1 + 0.001f * G2 * G2;
            float m3 = 0.9f * m2 + 0.1f * G3;
            float v3 = 0.999f * v2 + 0.001f * G3 * G3;
            float mh = m3 / 0.271f;
            float vh = v3 / 0.002997001f;
            go[c] = xs[n * 3 + c] - 0.01f * mh / (sqrtf(vh) + 1e-8f);
        }
    }
}

extern "C" void kernel_launch(void* const* d_in, const int* in_sizes, int n_in,
                              void* d_out, int out_size, void* d_ws, size_t ws_size,
                              hipStream_t stream) {
    const float* coords = (const float*)d_in[0];
    const float* restr  = (const float*)d_in[1];
    float* out = (float*)d_out;
    float* ws  = (float*)d_ws;
    float* g1  = ws;              // NEL floats
    float* g2  = ws + NEL;        // NEL floats

    void* args[] = { (void*)&coords, (void*)&restr, (void*)&g1, (void*)&g2, (void*)&out };
    hipLaunchCooperativeKernel((const void*)k_fused, dim3(GRID_), dim3(256),
                               args, 0, stream);
}

// Round 4
// 30.753 us; speedup vs baseline: 3.1918x; 3.1918x over previous
//
#include <hip/hip_runtime.h>

// GeometryRefiner: 3 Adam iterations on analytic gradient of
// bond + angle + clash + restraint loss. B=2, S=256, A=5.
// 3-dispatch chain, state materialized between kernels:
//   K1: grad(x0) -> g1, x1          (x1 = adam step1, own atoms)
//   K2: grad(x1) -> x2, m2, v2      (uses g1 per-own-atom)
//   K3: grad(x2) -> out             (uses m2,v2 per-own-atom)
// SPLIT=64: one full wave per atom (4 atoms / 256-thr block, 640 blocks).

#define S_ 256
#define A_ 5
#define NATOM 1280           // S_*A_
#define NB3 3840             // NATOM*3
#define NF4 960              // NB3/4
#define NEL 7680             // B*NB3
#define SPLIT 64
#define ATOMS_PER_BLOCK 4    // 256/SPLIT
#define BLOCKS_PER_BATCH 320 // NATOM/ATOMS_PER_BLOCK
#define GRID_ (2 * BLOCKS_PER_BATCH)

#define COEF_BOND2  (10.0f/1275.0f)
#define COEF_ANGLE2 (10.0f/1536.0f)
#define COEF_CLASH2 (20.0f/1619250.0f)
#define COEF_REST2  (2.0f/32640.0f)
#define TGT_ANG 1.91113553f               // 109.5 * pi / 180

__device__ __forceinline__ void angle_accum(const float* xs, int q, int role,
                                            float& gx, float& gy, float& gz) {
    const float* P = xs + (q - 1) * 3;
    const float* Q = xs + q * 3;
    const float* R = xs + (q + 1) * 3;
    float v1x = P[0] - Q[0], v1y = P[1] - Q[1], v1z = P[2] - Q[2];
    float v2x = R[0] - Q[0], v2y = R[1] - Q[1], v2z = R[2] - Q[2];
    float n1 = sqrtf(v1x * v1x + v1y * v1y + v1z * v1z);
    float n2 = sqrtf(v2x * v2x + v2y * v2y + v2z * v2z);
    float n1m = fmaxf(n1, 1e-8f), n2m = fmaxf(n2, 1e-8f);
    float dot = v1x * v2x + v1y * v2y + v1z * v2z;
    float inv1 = 1.0f / n1m, inv2 = 1.0f / n2m;
    float inv12 = inv1 * inv2;
    float cosv = dot * inv12;
    float cc = fminf(fmaxf(cosv, -1.0f), 1.0f);
    float ang = acosf(cc);
    float G = 0.0f;
    if (cosv > -1.0f && cosv < 1.0f) {
        G = -COEF_ANGLE2 * (ang - TGT_ANG) * rsqrtf(1.0f - cosv * cosv);
    }
    float a1 = cosv * inv1 * inv1, a2 = cosv * inv2 * inv2;
    float d1x = inv12 * v2x - a1 * v1x;
    float d1y = inv12 * v2y - a1 * v1y;
    float d1z = inv12 * v2z - a1 * v1z;
    float d2x = inv12 * v1x - a2 * v2x;
    float d2y = inv12 * v1y - a2 * v2y;
    float d2z = inv12 * v1z - a2 * v2z;
    if (role == 0)      { gx += G * d1x; gy += G * d1y; gz += G * d1z; }
    else if (role == 2) { gx += G * d2x; gy += G * d2y; gz += G * d2z; }
    else                { gx -= G * (d1x + d2x); gy -= G * (d1y + d2y); gz -= G * (d1z + d2z); }
}

// Full gradient for atom n; valid in (tx,ty,tz) at sub==0 after return.
__device__ __forceinline__ void grad_body(const float* xs, const float* rb,
                                          int n, int sub,
                                          float& tx, float& ty, float& tz) {
    const int s = n / A_;
    const int a = n - s * A_;
    const float xn0 = xs[n * 3], xn1 = xs[n * 3 + 1], xn2 = xs[n * 3 + 2];

    // clash partial over residues mr = sub, sub+64, sub+128, sub+192
    float cgx = 0.f, cgy = 0.f, cgz = 0.f;
    #pragma unroll
    for (int k = 0; k < S_ / SPLIT; ++k) {
        int mr = sub + k * SPLIT;
        int dres = mr - s;
        if (dres >= -1 && dres <= 1) continue;
        const float* xm = xs + mr * 15;
        #pragma unroll
        for (int ma = 0; ma < A_; ++ma) {
            float dx = xn0 - xm[ma * 3 + 0];
            float dy = xn1 - xm[ma * 3 + 1];
            float dz = xn2 - xm[ma * 3 + 2];
            float d2 = dx * dx + dy * dy + dz * dz;
            if (d2 > 1e-12f && d2 < 4.0f) {
                float inv = rsqrtf(d2);
                cgx += dx * inv; cgy += dy * inv; cgz += dz * inv;
            }
        }
    }

    // restraint partial (rep atoms only, a == 0; rep index i = s)
    float rgx = 0.f, rgy = 0.f, rgz = 0.f;
    if (a == 0) {
        const int i = s;
        #pragma unroll
        for (int k = 0; k < S_ / SPLIT; ++k) {
            int j = sub + k * SPLIT;
            if (j == i) continue;
            const float* xj = xs + j * 15;
            float dx = xn0 - xj[0], dy = xn1 - xj[1], dz = xn2 - xj[2];
            float d2 = dx * dx + dy * dy + dz * dz;
            if (d2 > 1e-12f) {
                float inv = rsqrtf(d2);
                float dr = d2 * inv;
                float rv = (i < j) ? rb[i * S_ + j] : rb[j * S_ + i];
                float w = (dr - rv) * inv;
                rgx += w * dx; rgy += w * dy; rgz += w * dz;
            }
        }
    }

    tx = -COEF_CLASH2 * cgx + COEF_REST2 * rgx;
    ty = -COEF_CLASH2 * cgy + COEF_REST2 * rgy;
    tz = -COEF_CLASH2 * cgz + COEF_REST2 * rgz;
    #pragma unroll
    for (int m = 1; m < SPLIT; m <<= 1) {
        tx += __shfl_xor(tx, m);
        ty += __shfl_xor(ty, m);
        tz += __shfl_xor(tz, m);
    }

    if (sub == 0) {
        if (n >= 1 && n <= 1275) {               // left bond (n-1, n)
            float dx = xn0 - xs[(n - 1) * 3];
            float dy = xn1 - xs[(n - 1) * 3 + 1];
            float dz = xn2 - xs[(n - 1) * 3 + 2];
            float d2 = dx * dx + dy * dy + dz * dz;
            float inv = rsqrtf(d2);
            float w = COEF_BOND2 * (1.0f - 1.5f * inv);
            tx += w * dx; ty += w * dy; tz += w * dz;
        }
        if (n <= 1274) {                         // right bond (n, n+1)
            float dx = xn0 - xs[(n + 1) * 3];
            float dy = xn1 - xs[(n + 1) * 3 + 1];
            float dz = xn2 - xs[(n + 1) * 3 + 2];
            float d2 = dx * dx + dy * dy + dz * dz;
            float inv = rsqrtf(d2);
            float w = COEF_BOND2 * (1.0f - 1.5f * inv);
            tx += w * dx; ty += w * dy; tz += w * dz;
        }
        if (a <= A_ - 3) angle_accum(xs, n + 1, 0, tx, ty, tz);
        if (a >= 1 && a <= A_ - 2) angle_accum(xs, n, 1, tx, ty, tz);
        if (a >= 2) angle_accum(xs, n - 1, 2, tx, ty, tz);
    }
}

// K1: g1 = grad(x0); x1 = adam1(x0, g1)   (own atoms)
__global__ __launch_bounds__(256) void k1(const float* __restrict__ x0,
                                          const float* __restrict__ restr,
                                          float* __restrict__ g1,
                                          float* __restrict__ x1) {
    __shared__ float xs[NB3];
    const int b = blockIdx.x / BLOCKS_PER_BATCH;
    const int base = (blockIdx.x % BLOCKS_PER_BATCH) * ATOMS_PER_BLOCK;
    const float* xb = x0 + b * NB3;
    for (int i = threadIdx.x; i < NF4; i += 256)
        ((float4*)xs)[i] = ((const float4*)xb)[i];
    __syncthreads();

    const int la = threadIdx.x >> 6;
    const int sub = threadIdx.x & (SPLIT - 1);
    const int n = base + la;
    float tx, ty, tz;
    grad_body(xs, restr + b * (S_ * S_), n, sub, tx, ty, tz);
    if (sub == 0) {
        const int idx = b * NB3 + n * 3;
        float g[3] = {tx, ty, tz};
        #pragma unroll
        for (int c = 0; c < 3; ++c) {
            float G = g[c];
            g1[idx + c] = G;
            float mh = (0.1f * G) / 0.1f;
            float vh = (0.001f * G * G) / 0.001f;
            x1[idx + c] = xs[n * 3 + c] - 0.01f * mh / (sqrtf(vh) + 1e-8f);
        }
    }
}

// K2: g2 = grad(x1); x2 = adam2 using stored g1; store m2, v2.
__global__ __launch_bounds__(256) void k2(const float* __restrict__ x1,
                                          const float* __restrict__ restr,
                                          const float* __restrict__ g1,
                                          float* __restrict__ x2,
                                          float* __restrict__ m2a,
                                          float* __restrict__ v2a) {
    __shared__ float xs[NB3];
    const int b = blockIdx.x / BLOCKS_PER_BATCH;
    const int base = (blockIdx.x % BLOCKS_PER_BATCH) * ATOMS_PER_BLOCK;
    const float* xb = x1 + b * NB3;
    for (int i = threadIdx.x; i < NF4; i += 256)
        ((float4*)xs)[i] = ((const float4*)xb)[i];
    __syncthreads();

    const int la = threadIdx.x >> 6;
    const int sub = threadIdx.x & (SPLIT - 1);
    const int n = base + la;
    float tx, ty, tz;
    grad_body(xs, restr + b * (S_ * S_), n, sub, tx, ty, tz);
    if (sub == 0) {
        const int idx = b * NB3 + n * 3;
        float g[3] = {tx, ty, tz};
        #pragma unroll
        for (int c = 0; c < 3; ++c) {
            float G1 = g1[idx + c], G2 = g[c];
            float m1 = 0.1f * G1;
            float v1 = 0.001f * G1 * G1;
            float m2 = 0.9f * m1 + 0.1f * G2;
            float v2 = 0.999f * v1 + 0.001f * G2 * G2;
            m2a[idx + c] = m2;
            v2a[idx + c] = v2;
            float mh = m2 / 0.19f;
            float vh = v2 / 0.001999f;
            x2[idx + c] = xs[n * 3 + c] - 0.01f * mh / (sqrtf(vh) + 1e-8f);
        }
    }
}

// K3: g3 = grad(x2); out = adam3 using stored m2, v2.
__global__ __launch_bounds__(256) void k3(const float* __restrict__ x2,
                                          const float* __restrict__ restr,
                                          const float* __restrict__ m2a,
                                          const float* __restrict__ v2a,
                                          float* __restrict__ out) {
    __shared__ float xs[NB3];
    const int b = blockIdx.x / BLOCKS_PER_BATCH;
    const int base = (blockIdx.x % BLOCKS_PER_BATCH) * ATOMS_PER_BLOCK;
    const float* xb = x2 + b * NB3;
    for (int i = threadIdx.x; i < NF4; i += 256)
        ((float4*)xs)[i] = ((const float4*)xb)[i];
    __syncthreads();

    const int la = threadIdx.x >> 6;
    const int sub = threadIdx.x & (SPLIT - 1);
    const int n = base + la;
    float tx, ty, tz;
    grad_body(xs, restr + b * (S_ * S_), n, sub, tx, ty, tz);
    if (sub == 0) {
        const int idx = b * NB3 + n * 3;
        float g[3] = {tx, ty, tz};
        #pragma unroll
        for (int c = 0; c < 3; ++c) {
            float G3 = g[c];
            float m3 = 0.9f * m2a[idx + c] + 0.1f * G3;
            float v3 = 0.999f * v2a[idx + c] + 0.001f * G3 * G3;
            float mh = m3 / 0.271f;
            float vh = v3 / 0.002997001f;
            out[idx + c] = xs[n * 3 + c] - 0.01f * mh / (sqrtf(vh) + 1e-8f);
        }
    }
}

extern "C" void kernel_launch(void* const* d_in, const int* in_sizes, int n_in,
                              void* d_out, int out_size, void* d_ws, size_t ws_size,
                              hipStream_t stream) {
    const float* coords = (const float*)d_in[0];
    const float* restr  = (const float*)d_in[1];
    float* out = (float*)d_out;
    float* ws  = (float*)d_ws;
    float* g1  = ws;              // NEL
    float* x1  = ws + NEL;        // NEL
    float* x2  = ws + 2 * NEL;    // NEL
    float* m2a = ws + 3 * NEL;    // NEL
    float* v2a = ws + 4 * NEL;    // NEL

    k1<<<GRID_, 256, 0, stream>>>(coords, restr, g1, x1);
    k2<<<GRID_, 256, 0, stream>>>(x1, restr, g1, x2, m2a, v2a);
    k3<<<GRID_, 256, 0, stream>>>(x2, restr, m2a, v2a, out);
}

// Round 5
// 25.229 us; speedup vs baseline: 3.8905x; 1.2189x over previous
//
#include <hip/hip_runtime.h>

// GeometryRefiner: 3 Adam iterations on analytic gradient of
// bond + angle + clash + restraint loss. B=2, S=256, A=5.
// 3-dispatch chain, state materialized between kernels:
//   K1: grad(x0) -> g1, x1
//   K2: grad(x1) -> x2, m2, v2
//   K3: grad(x2) -> out
// Block = 320 threads = 5 waves = 5 atoms (SPLIT=64: one wave per atom).
// 512 blocks = exactly 2 blocks/CU on 256 CUs -> uniform 10 waves/CU.
// Bond/angle terms computed pre-reduce on lanes 0-4 (unified bodies).

#define S_ 256
#define A_ 5
#define NATOM 1280           // S_*A_
#define NB3 3840             // NATOM*3
#define NF4 960              // NB3/4
#define NEL 7680             // B*NB3
#define SPLIT 64
#define BLOCK_ 320           // 5 waves
#define ATOMS_PER_BLOCK 5
#define BLOCKS_PER_BATCH 256 // NATOM/ATOMS_PER_BLOCK
#define GRID_ (2 * BLOCKS_PER_BATCH)

#define COEF_BOND2  (10.0f/1275.0f)
#define COEF_ANGLE2 (10.0f/1536.0f)
#define COEF_CLASH2 (20.0f/1619250.0f)
#define COEF_REST2  (2.0f/32640.0f)
#define TGT_ANG 1.91113553f               // 109.5 * pi / 180

__device__ __forceinline__ void angle_accum(const float* xs, int q, int role,
                                            float& gx, float& gy, float& gz) {
    const float* P = xs + (q - 1) * 3;
    const float* Q = xs + q * 3;
    const float* R = xs + (q + 1) * 3;
    float v1x = P[0] - Q[0], v1y = P[1] - Q[1], v1z = P[2] - Q[2];
    float v2x = R[0] - Q[0], v2y = R[1] - Q[1], v2z = R[2] - Q[2];
    float n1 = sqrtf(v1x * v1x + v1y * v1y + v1z * v1z);
    float n2 = sqrtf(v2x * v2x + v2y * v2y + v2z * v2z);
    float n1m = fmaxf(n1, 1e-8f), n2m = fmaxf(n2, 1e-8f);
    float dot = v1x * v2x + v1y * v2y + v1z * v2z;
    float inv1 = 1.0f / n1m, inv2 = 1.0f / n2m;
    float inv12 = inv1 * inv2;
    float cosv = dot * inv12;
    float cc = fminf(fmaxf(cosv, -1.0f), 1.0f);
    float ang = acosf(cc);
    float G = 0.0f;
    if (cosv > -1.0f && cosv < 1.0f) {
        G = -COEF_ANGLE2 * (ang - TGT_ANG) * rsqrtf(1.0f - cosv * cosv);
    }
    float a1 = cosv * inv1 * inv1, a2 = cosv * inv2 * inv2;
    float d1x = inv12 * v2x - a1 * v1x;
    float d1y = inv12 * v2y - a1 * v1y;
    float d1z = inv12 * v2z - a1 * v1z;
    float d2x = inv12 * v1x - a2 * v2x;
    float d2y = inv12 * v1y - a2 * v2y;
    float d2z = inv12 * v1z - a2 * v2z;
    if (role == 0)      { gx += G * d1x; gy += G * d1y; gz += G * d1z; }
    else if (role == 2) { gx += G * d2x; gy += G * d2y; gz += G * d2z; }
    else                { gx -= G * (d1x + d2x); gy -= G * (d1y + d2y); gz -= G * (d1z + d2z); }
}

// Full gradient for atom n; valid in (tx,ty,tz) at sub==0 after return.
__device__ __forceinline__ void grad_body(const float* xs, const float* rb,
                                          int n, int sub,
                                          float& tx, float& ty, float& tz) {
    const int s = n / A_;
    const int a = n - s * A_;
    const float xn0 = xs[n * 3], xn1 = xs[n * 3 + 1], xn2 = xs[n * 3 + 2];

    // clash partial over residues mr = sub, sub+64, sub+128, sub+192
    float cgx = 0.f, cgy = 0.f, cgz = 0.f;
    #pragma unroll
    for (int k = 0; k < S_ / SPLIT; ++k) {
        int mr = sub + k * SPLIT;
        int dres = mr - s;
        if (dres >= -1 && dres <= 1) continue;
        const float* xm = xs + mr * 15;
        #pragma unroll
        for (int ma = 0; ma < A_; ++ma) {
            float dx = xn0 - xm[ma * 3 + 0];
            float dy = xn1 - xm[ma * 3 + 1];
            float dz = xn2 - xm[ma * 3 + 2];
            float d2 = dx * dx + dy * dy + dz * dz;
            if (d2 > 1e-12f && d2 < 4.0f) {
                float inv = rsqrtf(d2);
                cgx += dx * inv; cgy += dy * inv; cgz += dz * inv;
            }
        }
    }

    // restraint partial (rep atoms only, a == 0; rep index i = s)
    float rgx = 0.f, rgy = 0.f, rgz = 0.f;
    if (a == 0) {
        const int i = s;
        #pragma unroll
        for (int k = 0; k < S_ / SPLIT; ++k) {
            int j = sub + k * SPLIT;
            if (j == i) continue;
            const float* xj = xs + j * 15;
            float dx = xn0 - xj[0], dy = xn1 - xj[1], dz = xn2 - xj[2];
            float d2 = dx * dx + dy * dy + dz * dz;
            if (d2 > 1e-12f) {
                float inv = rsqrtf(d2);
                float dr = d2 * inv;
                float rv = (i < j) ? rb[i * S_ + j] : rb[j * S_ + i];
                float w = (dr - rv) * inv;
                rgx += w * dx; rgy += w * dy; rgz += w * dz;
            }
        }
    }

    tx = -COEF_CLASH2 * cgx + COEF_REST2 * rgx;
    ty = -COEF_CLASH2 * cgy + COEF_REST2 * rgy;
    tz = -COEF_CLASH2 * cgz + COEF_REST2 * rgz;

    // bonds on lanes 0,1 (unified body: neighbor = n-1 / n+1)
    if (sub < 2) {
        bool valid = (sub == 0) ? (n >= 1 && n <= 1275) : (n <= 1274);
        if (valid) {
            int nb = (sub == 0) ? n - 1 : n + 1;
            float dx = xn0 - xs[nb * 3];
            float dy = xn1 - xs[nb * 3 + 1];
            float dz = xn2 - xs[nb * 3 + 2];
            float d2 = dx * dx + dy * dy + dz * dz;
            float inv = rsqrtf(d2);
            float w = COEF_BOND2 * (1.0f - 1.5f * inv);
            tx += w * dx; ty += w * dy; tz += w * dz;
        }
    }
    // angles on lanes 2,3,4 (unified body: q = n+1-role)
    if (sub >= 2 && sub <= 4) {
        int role = sub - 2;
        bool valid = (role == 0) ? (a <= A_ - 3)
                   : (role == 1) ? (a >= 1 && a <= A_ - 2)
                                 : (a >= 2);
        if (valid) angle_accum(xs, n + 1 - role, role, tx, ty, tz);
    }

    #pragma unroll
    for (int m = 1; m < SPLIT; m <<= 1) {
        tx += __shfl_xor(tx, m);
        ty += __shfl_xor(ty, m);
        tz += __shfl_xor(tz, m);
    }
}

// K1: g1 = grad(x0); x1 = adam1(x0, g1)
__global__ __launch_bounds__(BLOCK_) void k1(const float* __restrict__ x0,
                                             const float* __restrict__ restr,
                                             float* __restrict__ g1,
                                             float* __restrict__ x1) {
    __shared__ float xs[NB3];
    const int b = blockIdx.x / BLOCKS_PER_BATCH;
    const int base = (blockIdx.x % BLOCKS_PER_BATCH) * ATOMS_PER_BLOCK;
    const float* xb = x0 + b * NB3;
    for (int i = threadIdx.x; i < NF4; i += BLOCK_)
        ((float4*)xs)[i] = ((const float4*)xb)[i];
    __syncthreads();

    const int la = threadIdx.x >> 6;
    const int sub = threadIdx.x & (SPLIT - 1);
    const int n = base + la;
    float tx, ty, tz;
    grad_body(xs, restr + b * (S_ * S_), n, sub, tx, ty, tz);
    if (sub == 0) {
        const int idx = b * NB3 + n * 3;
        float g[3] = {tx, ty, tz};
        #pragma unroll
        for (int c = 0; c < 3; ++c) {
            float G = g[c];
            g1[idx + c] = G;
            float mh = (0.1f * G) / 0.1f;
            float vh = (0.001f * G * G) / 0.001f;
            x1[idx + c] = xs[n * 3 + c] - 0.01f * mh / (sqrtf(vh) + 1e-8f);
        }
    }
}

// K2: g2 = grad(x1); x2 = adam2 using stored g1; store m2, v2.
__global__ __launch_bounds__(BLOCK_) void k2(const float* __restrict__ x1,
                                             const float* __restrict__ restr,
                                             const float* __restrict__ g1,
                                             float* __restrict__ x2,
                                             float* __restrict__ m2a,
                                             float* __restrict__ v2a) {
    __shared__ float xs[NB3];
    const int b = blockIdx.x / BLOCKS_PER_BATCH;
    const int base = (blockIdx.x % BLOCKS_PER_BATCH) * ATOMS_PER_BLOCK;
    const int la = threadIdx.x >> 6;
    const int sub = threadIdx.x & (SPLIT - 1);
    const int n = base + la;
    const int idx = b * NB3 + n * 3;
    // prefetch adam state early (wave-uniform address -> broadcast)
    float P0 = g1[idx], P1 = g1[idx + 1], P2 = g1[idx + 2];

    const float* xb = x1 + b * NB3;
    for (int i = threadIdx.x; i < NF4; i += BLOCK_)
        ((float4*)xs)[i] = ((const float4*)xb)[i];
    __syncthreads();

    float tx, ty, tz;
    grad_body(xs, restr + b * (S_ * S_), n, sub, tx, ty, tz);
    if (sub == 0) {
        float g[3] = {tx, ty, tz};
        float G1c[3] = {P0, P1, P2};
        #pragma unroll
        for (int c = 0; c < 3; ++c) {
            float G1 = G1c[c], G2 = g[c];
            float m1 = 0.1f * G1;
            float v1 = 0.001f * G1 * G1;
            float m2 = 0.9f * m1 + 0.1f * G2;
            float v2 = 0.999f * v1 + 0.001f * G2 * G2;
            m2a[idx + c] = m2;
            v2a[idx + c] = v2;
            float mh = m2 / 0.19f;
            float vh = v2 / 0.001999f;
            x2[idx + c] = xs[n * 3 + c] - 0.01f * mh / (sqrtf(vh) + 1e-8f);
        }
    }
}

// K3: g3 = grad(x2); out = adam3 using stored m2, v2.
__global__ __launch_bounds__(BLOCK_) void k3(const float* __restrict__ x2,
                                             const float* __restrict__ restr,
                                             const float* __restrict__ m2a,
                                             const float* __restrict__ v2a,
                                             float* __restrict__ out) {
    __shared__ float xs[NB3];
    const int b = blockIdx.x / BLOCKS_PER_BATCH;
    const int base = (blockIdx.x % BLOCKS_PER_BATCH) * ATOMS_PER_BLOCK;
    const int la = threadIdx.x >> 6;
    const int sub = threadIdx.x & (SPLIT - 1);
    const int n = base + la;
    const int idx = b * NB3 + n * 3;
    // prefetch adam state early
    float M0 = m2a[idx], M1 = m2a[idx + 1], M2 = m2a[idx + 2];
    float V0 = v2a[idx], V1 = v2a[idx + 1], V2 = v2a[idx + 2];

    const float* xb = x2 + b * NB3;
    for (int i = threadIdx.x; i < NF4; i += BLOCK_)
        ((float4*)xs)[i] = ((const float4*)xb)[i];
    __syncthreads();

    float tx, ty, tz;
    grad_body(xs, restr + b * (S_ * S_), n, sub, tx, ty, tz);
    if (sub == 0) {
        float g[3] = {tx, ty, tz};
        float Mc[3] = {M0, M1, M2};
        float Vc[3] = {V0, V1, V2};
        #pragma unroll
        for (int c = 0; c < 3; ++c) {
            float G3 = g[c];
            float m3 = 0.9f * Mc[c] + 0.1f * G3;
            float v3 = 0.999f * Vc[c] + 0.001f * G3 * G3;
            float mh = m3 / 0.271f;
            float vh = v3 / 0.002997001f;
            out[idx + c] = xs[n * 3 + c] - 0.01f * mh / (sqrtf(vh) + 1e-8f);
        }
    }
}

extern "C" void kernel_launch(void* const* d_in, const int* in_sizes, int n_in,
                              void* d_out, int out_size, void* d_ws, size_t ws_size,
                              hipStream_t stream) {
    const float* coords = (const float*)d_in[0];
    const float* restr  = (const float*)d_in[1];
    float* out = (float*)d_out;
    float* ws  = (float*)d_ws;
    float* g1  = ws;              // NEL
    float* x1  = ws + NEL;        // NEL
    float* x2  = ws + 2 * NEL;    // NEL
    float* m2a = ws + 3 * NEL;    // NEL
    float* v2a = ws + 4 * NEL;    // NEL

    k1<<<GRID_, BLOCK_, 0, stream>>>(coords, restr, g1, x1);
    k2<<<GRID_, BLOCK_, 0, stream>>>(x1, restr, g1, x2, m2a, v2a);
    k3<<<GRID_, BLOCK_, 0, stream>>>(x2, restr, m2a, v2a, out);
}

// Round 6
// 22.067 us; speedup vs baseline: 4.4481x; 1.1433x over previous
//
#include <hip/hip_runtime.h>

// GeometryRefiner: 3 Adam iterations on analytic gradient of
// bond + angle + clash + restraint loss. B=2, S=256, A=5.
// 3-dispatch chain (structural minimum: each iteration is a global
// all-to-all dependency; in-kernel grid sync measured 5x slower).
//   K1: grad(x0) -> g1, x1
//   K2: grad(x1) -> x2, m2, v2
//   K3: grad(x2) -> out
// Block = 320 threads = 5 waves = 5 atoms (SPLIT=64: one wave per atom).
// 512 blocks = exactly 2 blocks/CU -> uniform 10 waves/CU.
// Stage via global_load_lds; epilogue spread across lanes 0-2.

#define S_ 256
#define A_ 5
#define NATOM 1280           // S_*A_
#define NB3 3840             // NATOM*3
#define NF4 960              // NB3/4
#define NEL 7680             // B*NB3
#define SPLIT 64
#define BLOCK_ 320           // 5 waves
#define ATOMS_PER_BLOCK 5
#define BLOCKS_PER_BATCH 256 // NATOM/ATOMS_PER_BLOCK
#define GRID_ (2 * BLOCKS_PER_BATCH)

#define COEF_BOND2  (10.0f/1275.0f)
#define COEF_ANGLE2 (10.0f/1536.0f)
#define COEF_CLASH2 (20.0f/1619250.0f)
#define COEF_REST2  (2.0f/32640.0f)
#define TGT_ANG 1.91113553f               // 109.5 * pi / 180

__device__ __forceinline__ void stage_lds(float* xs, const float* xb, int tid) {
    // 960 float4 chunks, 320 threads, 3 iterations. For wave w, iter k:
    // chunk = w*64 + lane + k*320 -> LDS byte offset = chunk*16 =
    // (wave-uniform) + lane*16, satisfying global_load_lds addressing.
    #pragma unroll
    for (int k = 0; k < 3; ++k) {
        int c = tid + k * BLOCK_;
        __builtin_amdgcn_global_load_lds((const __attribute__((address_space(1))) void*)(xb + c * 4),
                                         (__attribute__((address_space(3))) void*)(xs + c * 4),
                                         16, 0, 0);
    }
    __builtin_amdgcn_s_waitcnt(0x3f70 /* vmcnt(0) */);
    __syncthreads();
}

__device__ __forceinline__ void angle_accum(const float* xs, int q, int role,
                                            float& gx, float& gy, float& gz) {
    const float* P = xs + (q - 1) * 3;
    const float* Q = xs + q * 3;
    const float* R = xs + (q + 1) * 3;
    float v1x = P[0] - Q[0], v1y = P[1] - Q[1], v1z = P[2] - Q[2];
    float v2x = R[0] - Q[0], v2y = R[1] - Q[1], v2z = R[2] - Q[2];
    float n1 = sqrtf(v1x * v1x + v1y * v1y + v1z * v1z);
    float n2 = sqrtf(v2x * v2x + v2y * v2y + v2z * v2z);
    float n1m = fmaxf(n1, 1e-8f), n2m = fmaxf(n2, 1e-8f);
    float dot = v1x * v2x + v1y * v2y + v1z * v2z;
    float inv1 = 1.0f / n1m, inv2 = 1.0f / n2m;
    float inv12 = inv1 * inv2;
    float cosv = dot * inv12;
    float cc = fminf(fmaxf(cosv, -1.0f), 1.0f);
    float ang = acosf(cc);
    float G = 0.0f;
    if (cosv > -1.0f && cosv < 1.0f) {
        G = -COEF_ANGLE2 * (ang - TGT_ANG) * rsqrtf(1.0f - cosv * cosv);
    }
    float a1 = cosv * inv1 * inv1, a2 = cosv * inv2 * inv2;
    float d1x = inv12 * v2x - a1 * v1x;
    float d1y = inv12 * v2y - a1 * v1y;
    float d1z = inv12 * v2z - a1 * v1z;
    float d2x = inv12 * v1x - a2 * v2x;
    float d2y = inv12 * v1y - a2 * v2y;
    float d2z = inv12 * v1z - a2 * v2z;
    if (role == 0)      { gx += G * d1x; gy += G * d1y; gz += G * d1z; }
    else if (role == 2) { gx += G * d2x; gy += G * d2y; gz += G * d2z; }
    else                { gx -= G * (d1x + d2x); gy -= G * (d1y + d2y); gz -= G * (d1z + d2z); }
}

// Full gradient for atom n; after return ALL lanes hold the reduced sum.
__device__ __forceinline__ void grad_body(const float* xs, const float* rb,
                                          int n, int sub,
                                          float& tx, float& ty, float& tz) {
    const int s = n / A_;
    const int a = n - s * A_;
    const float xn0 = xs[n * 3], xn1 = xs[n * 3 + 1], xn2 = xs[n * 3 + 2];

    // clash partial over residues mr = sub, sub+64, sub+128, sub+192
    float cgx = 0.f, cgy = 0.f, cgz = 0.f;
    #pragma unroll
    for (int k = 0; k < S_ / SPLIT; ++k) {
        int mr = sub + k * SPLIT;
        int dres = mr - s;
        if (dres >= -1 && dres <= 1) continue;
        const float* xm = xs + mr * 15;
        #pragma unroll
        for (int ma = 0; ma < A_; ++ma) {
            float dx = xn0 - xm[ma * 3 + 0];
            float dy = xn1 - xm[ma * 3 + 1];
            float dz = xn2 - xm[ma * 3 + 2];
            float d2 = dx * dx + dy * dy + dz * dz;
            if (d2 > 1e-12f && d2 < 4.0f) {
                float inv = rsqrtf(d2);
                cgx += dx * inv; cgy += dy * inv; cgz += dz * inv;
            }
        }
    }

    // restraint partial (rep atoms only, a == 0; rep index i = s)
    float rgx = 0.f, rgy = 0.f, rgz = 0.f;
    if (a == 0) {
        const int i = s;
        #pragma unroll
        for (int k = 0; k < S_ / SPLIT; ++k) {
            int j = sub + k * SPLIT;
            if (j == i) continue;
            const float* xj = xs + j * 15;
            float dx = xn0 - xj[0], dy = xn1 - xj[1], dz = xn2 - xj[2];
            float d2 = dx * dx + dy * dy + dz * dz;
            if (d2 > 1e-12f) {
                float inv = rsqrtf(d2);
                float dr = d2 * inv;
                float rv = (i < j) ? rb[i * S_ + j] : rb[j * S_ + i];
                float w = (dr - rv) * inv;
                rgx += w * dx; rgy += w * dy; rgz += w * dz;
            }
        }
    }

    tx = -COEF_CLASH2 * cgx + COEF_REST2 * rgx;
    ty = -COEF_CLASH2 * cgy + COEF_REST2 * rgy;
    tz = -COEF_CLASH2 * cgz + COEF_REST2 * rgz;

    // bonds on lanes 0,1 (unified body: neighbor = n-1 / n+1)
    if (sub < 2) {
        bool valid = (sub == 0) ? (n >= 1 && n <= 1275) : (n <= 1274);
        if (valid) {
            int nb = (sub == 0) ? n - 1 : n + 1;
            float dx = xn0 - xs[nb * 3];
            float dy = xn1 - xs[nb * 3 + 1];
            float dz = xn2 - xs[nb * 3 + 2];
            float d2 = dx * dx + dy * dy + dz * dz;
            float inv = rsqrtf(d2);
            float w = COEF_BOND2 * (1.0f - 1.5f * inv);
            tx += w * dx; ty += w * dy; tz += w * dz;
        }
    }
    // angles on lanes 2,3,4 (unified body: q = n+1-role)
    if (sub >= 2 && sub <= 4) {
        int role = sub - 2;
        bool valid = (role == 0) ? (a <= A_ - 3)
                   : (role == 1) ? (a >= 1 && a <= A_ - 2)
                                 : (a >= 2);
        if (valid) angle_accum(xs, n + 1 - role, role, tx, ty, tz);
    }

    #pragma unroll
    for (int m = 1; m < SPLIT; m <<= 1) {
        tx += __shfl_xor(tx, m);
        ty += __shfl_xor(ty, m);
        tz += __shfl_xor(tz, m);
    }
}

// K1: g1 = grad(x0); x1 = adam1(x0, g1)
__global__ __launch_bounds__(BLOCK_) void k1(const float* __restrict__ x0,
                                             const float* __restrict__ restr,
                                             float* __restrict__ g1,
                                             float* __restrict__ x1) {
    __shared__ float xs[NB3];
    const int b = blockIdx.x / BLOCKS_PER_BATCH;
    const int base = (blockIdx.x % BLOCKS_PER_BATCH) * ATOMS_PER_BLOCK;
    stage_lds(xs, x0 + b * NB3, threadIdx.x);

    const int la = threadIdx.x >> 6;
    const int sub = threadIdx.x & (SPLIT - 1);
    const int n = base + la;
    float tx, ty, tz;
    grad_body(xs, restr + b * (S_ * S_), n, sub, tx, ty, tz);
    if (sub < 3) {
        const int idx = b * NB3 + n * 3 + sub;
        float G = (sub == 0) ? tx : (sub == 1) ? ty : tz;
        g1[idx] = G;
        float mh = (0.1f * G) / 0.1f;
        float vh = (0.001f * G * G) / 0.001f;
        x1[idx] = xs[n * 3 + sub] - 0.01f * mh / (sqrtf(vh) + 1e-8f);
    }
}

// K2: g2 = grad(x1); x2 = adam2 using stored g1; store m2, v2.
__global__ __launch_bounds__(BLOCK_) void k2(const float* __restrict__ x1,
                                             const float* __restrict__ restr,
                                             const float* __restrict__ g1,
                                             float* __restrict__ x2,
                                             float* __restrict__ m2a,
                                             float* __restrict__ v2a) {
    __shared__ float xs[NB3];
    const int b = blockIdx.x / BLOCKS_PER_BATCH;
    const int base = (blockIdx.x % BLOCKS_PER_BATCH) * ATOMS_PER_BLOCK;
    const int la = threadIdx.x >> 6;
    const int sub = threadIdx.x & (SPLIT - 1);
    const int n = base + la;
    const int idx = b * NB3 + n * 3 + ((sub < 3) ? sub : 0);
    // prefetch adam state early (L2-warm broadcast within lane triple)
    float G1 = g1[idx];

    stage_lds(xs, x1 + b * NB3, threadIdx.x);

    float tx, ty, tz;
    grad_body(xs, restr + b * (S_ * S_), n, sub, tx, ty, tz);
    if (sub < 3) {
        float G2 = (sub == 0) ? tx : (sub == 1) ? ty : tz;
        float m1 = 0.1f * G1;
        float v1 = 0.001f * G1 * G1;
        float m2 = 0.9f * m1 + 0.1f * G2;
        float v2 = 0.999f * v1 + 0.001f * G2 * G2;
        m2a[idx] = m2;
        v2a[idx] = v2;
        float mh = m2 / 0.19f;
        float vh = v2 / 0.001999f;
        x2[idx] = xs[n * 3 + sub] - 0.01f * mh / (sqrtf(vh) + 1e-8f);
    }
}

// K3: g3 = grad(x2); out = adam3 using stored m2, v2.
__global__ __launch_bounds__(BLOCK_) void k3(const float* __restrict__ x2,
                                             const float* __restrict__ restr,
                                             const float* __restrict__ m2a,
                                             const float* __restrict__ v2a,
                                             float* __restrict__ out) {
    __shared__ float xs[NB3];
    const int b = blockIdx.x / BLOCKS_PER_BATCH;
    const int base = (blockIdx.x % BLOCKS_PER_BATCH) * ATOMS_PER_BLOCK;
    const int la = threadIdx.x >> 6;
    const int sub = threadIdx.x & (SPLIT - 1);
    const int n = base + la;
    const int idx = b * NB3 + n * 3 + ((sub < 3) ? sub : 0);
    // prefetch adam state early
    float M = m2a[idx];
    float V = v2a[idx];

    stage_lds(xs, x2 + b * NB3, threadIdx.x);

    float tx, ty, tz;
    grad_body(xs, restr + b * (S_ * S_), n, sub, tx, ty, tz);
    if (sub < 3) {
        float G3 = (sub == 0) ? tx : (sub == 1) ? ty : tz;
        float m3 = 0.9f * M + 0.1f * G3;
        float v3 = 0.999f * V + 0.001f * G3 * G3;
        float mh = m3 / 0.271f;
        float vh = v3 / 0.002997001f;
        out[idx] = xs[n * 3 + sub] - 0.01f * mh / (sqrtf(vh) + 1e-8f);
    }
}

extern "C" void kernel_launch(void* const* d_in, const int* in_sizes, int n_in,
                              void* d_out, int out_size, void* d_ws, size_t ws_size,
                              hipStream_t stream) {
    const float* coords = (const float*)d_in[0];
    const float* restr  = (const float*)d_in[1];
    float* out = (float*)d_out;
    float* ws  = (float*)d_ws;
    float* g1  = ws;              // NEL
    float* x1  = ws + NEL;        // NEL
    float* x2  = ws + 2 * NEL;    // NEL
    float* m2a = ws + 3 * NEL;    // NEL
    float* v2a = ws + 4 * NEL;    // NEL

    k1<<<GRID_, BLOCK_, 0, stream>>>(coords, restr, g1, x1);
    k2<<<GRID_, BLOCK_, 0, stream>>>(x1, restr, g1, x2, m2a, v2a);
    k3<<<GRID_, BLOCK_, 0, stream>>>(x2, restr, m2a, v2a, out);
}